// Round 11
// baseline (521.478 us; speedup 1.0000x reference)
//
#include <hip/hip_runtime.h>
#include <hip/hip_bf16.h>
#include <stdint.h>

#define B_   64
#define T_   2048
#define ENC_ 1024
#define DEC_ 1024
#define A_   512
#define M_   (B_ * T_)   // 131072

#define BM 128
#define BN 128
#define BK 32
#define NT (ENC_ / BK)   // 32 K-tiles

typedef __bf16 bf16x8 __attribute__((ext_vector_type(8)));
typedef float  f32x4  __attribute__((ext_vector_type(4)));
typedef unsigned short u16;
typedef u16 u16x8 __attribute__((ext_vector_type(8)));

__device__ __forceinline__ float fast_tanh(float x) {
    float ax = fabsf(x);
    float e  = __expf(-2.0f * ax);     // in (0,1]
    float t  = (1.0f - e) / (1.0f + e);
    return copysignf(t, x);
}

// ---------------- U transpose + convert: Ut[n][k] = bf16(U[k][n]) ----------
__global__ __launch_bounds__(256) void k_transpose_U(
        const float* __restrict__ U, u16* __restrict__ Ut) {
    int idx = blockIdx.x * 256 + threadIdx.x;     // over 1024*512
    if (idx >= ENC_ * A_) return;
    int k = idx / A_, n = idx % A_;
    __bf16 v = (__bf16)U[idx];
    Ut[n * ENC_ + k] = *(u16*)&v;
}

// ---------------- f2[b][a] = sum_e s[b][e] * W[e][a]  (fp32) ---------------
__global__ __launch_bounds__(256) void k_f2(
        const float* __restrict__ s, const float* __restrict__ W,
        float* __restrict__ f2) {
    int b = blockIdx.x;
    int a0 = threadIdx.x;
    const float* srow = s + (size_t)b * DEC_;
    float acc0 = 0.f, acc1 = 0.f;
    for (int e = 0; e < DEC_; ++e) {
        float sv = srow[e];
        acc0 = fmaf(sv, W[(size_t)e * A_ + a0],       acc0);
        acc1 = fmaf(sv, W[(size_t)e * A_ + a0 + 256], acc1);
    }
    f2[(size_t)b * A_ + a0]       = acc0;
    f2[(size_t)b * A_ + a0 + 256] = acc1;
}

// ---------------- fused GEMM + tanh + dot(V): partial e --------------------
// 4096 blocks x 256 threads (4 waves, 2x2), wave tile 64x64 (acc = 64 AGPR).
// BM=128 BN=128 BK=32, LDS = dbuf(A 8KB + B 8KB) = 32 KB -> 4 blocks/CU.
// ONE s_barrier per K-tile, counted vmcnt (never 0 in steady state):
//   tile t: stageB(t+1)->Bb[o] (2 gload_lds, fly under compute)
//           compute(cur)  (8 ds_read_b128 + 16 MFMA)
//           writeA(t+1)   (reg-dep wait drains A(t+1) only - A older than B)
//           loadA(t+2)    (4 global loads, fly across barrier)
//           VMC(4) [B(t+1) done, A(t+2) in flight]; LGKM0; BAR
// 4 desynced blocks/CU keep HBM loads outstanding continuously (the R7->R6
// lesson: duty cycle, not MFMA scheduling, limits this HBM-bound GEMM).
// Swizzle (BK=32): phys_u16 = flat ^ ((row&3)<<3); B source pre-swizzled.
__global__ __launch_bounds__(256, 8) void k_gemm_e(
        const float* __restrict__ h, const u16* __restrict__ Ut,
        const float* __restrict__ f2, const float* __restrict__ V,
        float* __restrict__ e_part) {
    __shared__ u16 Ab[2][BM * BK];     // 2 x 8 KB
    __shared__ u16 Bb[2][BN * BK];     // 2 x 8 KB

    const int tid  = threadIdx.x;
    const int lane = tid & 63;
    const int wid  = tid >> 6;         // 0..3
    const int wr   = wid >> 1;         // 0..1
    const int wc   = wid & 1;          // 0..1
    const int lr   = lane & 15;
    const int g    = lane >> 4;        // 0..3
    const int swr  = (lr & 3) << 3;    // read-side XOR (u16 units)

    // XCD-aware remap: 4 col-blocks of a row-panel adjacent on one XCD.
    const int d    = blockIdx.x;       // 0..4095
    const int xcd  = d & 7;
    const int s    = d >> 3;           // 0..511 per XCD
    const int m    = s & 3;            // col-block 0..3
    const int pr   = xcd * 128 + (s >> 2);   // row-panel 0..1023
    const int brow = pr * BM;
    const int bcol = m * BN;
    const int b    = brow / T_;        // uniform per block (T_ % BM == 0)

    f32x4 acc[4][4] = {};              // 64 f32 -> AGPRs
    f32x4 ar[4];                       // in-flight A: 16 floats/thread

    const int arow = tid >> 1;               // 0..127
    const int acol = (tid & 1) << 4;         // 0 or 16
    auto loadA = [&](int kt) {
        const float* src = h + (size_t)(brow + arow) * ENC_ + kt * BK + acol;
        ar[0] = *(const f32x4*)src;       ar[1] = *(const f32x4*)(src + 4);
        ar[2] = *(const f32x4*)(src + 8); ar[3] = *(const f32x4*)(src + 12);
    };
    auto writeA = [&](u16* A) {
        int cb = (tid & 1) << 1;             // chunk base 0 or 2
        u16x8 w0, w1;
#pragma unroll
        for (int j = 0; j < 4; ++j) {
            __bf16 a0 = (__bf16)ar[0][j], a1 = (__bf16)ar[1][j];
            __bf16 a2 = (__bf16)ar[2][j], a3 = (__bf16)ar[3][j];
            w0[j] = *(u16*)&a0; w0[j + 4] = *(u16*)&a1;
            w1[j] = *(u16*)&a2; w1[j + 4] = *(u16*)&a3;
        }
        *(u16x8*)&A[arow * 32 + ((cb     ^ (arow & 3)) << 3)] = w0;
        *(u16x8*)&A[arow * 32 + ((cb + 1) ^ (arow & 3) ) * 8] = w1;
    };
    auto stageB = [&](u16* Bd, int kt) {
#pragma unroll
        for (int it = 0; it < 2; ++it) {
            int G  = it * 256 + tid;                  // 16B granule
            int n  = G >> 2;
            int kc = ((G & 3) ^ (n & 3)) << 3;        // pre-swizzled source
            const u16* src = Ut + (size_t)(bcol + n) * ENC_ + kt * BK + kc;
            u16* dst = &Bd[(size_t)(it * 256 + wid * 64) * 8];
            __builtin_amdgcn_global_load_lds(
                (const __attribute__((address_space(1))) void*)src,
                (__attribute__((address_space(3))) void*)dst, 16, 0, 0);
        }
    };
    auto compute = [&](const u16* A, const u16* Bc) {
        bf16x8 af[4], bfr[4];
#pragma unroll
        for (int mf = 0; mf < 4; ++mf) {
            int row = wr * 64 + mf * 16 + lr;         // row&3 == lr&3
            af[mf] = *(const bf16x8*)&A[(row * 32 + g * 8) ^ swr];
        }
#pragma unroll
        for (int nf = 0; nf < 4; ++nf) {
            int n = wc * 64 + nf * 16 + lr;
            bfr[nf] = *(const bf16x8*)&Bc[(n * 32 + g * 8) ^ swr];
        }
#pragma unroll
        for (int mf = 0; mf < 4; ++mf)
#pragma unroll
            for (int nf = 0; nf < 4; ++nf)
                acc[mf][nf] = __builtin_amdgcn_mfma_f32_16x16x32_bf16(
                    af[mf], bfr[nf], acc[mf][nf], 0, 0, 0);
    };

#define BAR()   __builtin_amdgcn_s_barrier()
#define LGKM0() asm volatile("s_waitcnt lgkmcnt(0)" ::: "memory")
#define VMC4()  asm volatile("s_waitcnt vmcnt(4)" ::: "memory")
#define VMC0()  asm volatile("s_waitcnt vmcnt(0)" ::: "memory")

    // ---- prologue ----
    loadA(0);                 // A(0) -> regs (oldest in queue)
    stageB(Bb[0], 0);         // B(0) in flight
    writeA(Ab[0]);            // waits A(0) regs only; B(0) stays in flight
    loadA(1);                 // A(1) in flight
    VMC4();                   // outstanding = B(0)+A(1)=6 -> wait leaves 4:
                              // B(0) done (A(1)'s 4 newer) ; A(1) flying
    LGKM0(); BAR();

    for (int t = 0; t < NT; ++t) {
        const int cur = t & 1;
        if (t + 1 < NT) stageB(Bb[cur ^ 1], t + 1);   // fly under compute
        compute(Ab[cur], Bb[cur]);
        if (t + 1 < NT) {
            writeA(Ab[cur ^ 1]);          // waits A(t+1) regs (older than B)
            if (t + 2 < NT) {
                loadA(t + 2);
                VMC4();                   // B(t+1) done; A(t+2) in flight
            } else {
                VMC0();                   // last staged tile: full drain
            }
            LGKM0(); BAR();
        }
    }

    // ---- epilogue: e_partial[m] = sum_n tanh(acc + f2) * V ----
    float vv[4], ff[4];
#pragma unroll
    for (int nf = 0; nf < 4; ++nf) {
        int n = bcol + wc * 64 + nf * 16 + lr;
        vv[nf] = V[n];
        ff[nf] = f2[(size_t)b * A_ + n];
    }
    const int p = m * 2 + wc;                     // 8 partial slices (64 cols)
    float* ep = e_part + (size_t)p * M_ + brow + wr * 64;
#pragma unroll
    for (int mf = 0; mf < 4; ++mf) {
        float sums[4];
#pragma unroll
        for (int i = 0; i < 4; ++i) {
            float sv = 0.f;
#pragma unroll
            for (int nf = 0; nf < 4; ++nf) {
                float x = acc[mf][nf][i] + ff[nf];
                sv = fmaf(fast_tanh(x), vv[nf], sv);
            }
#pragma unroll
            for (int mm = 1; mm < 16; mm <<= 1)
                sv += __shfl_xor(sv, mm, 64);     // reduce 16 cols
            sums[i] = sv;
        }
        if (lr == 0) {
#pragma unroll
            for (int i = 0; i < 4; ++i)
                ep[mf * 16 + g * 4 + i] = sums[i];
        }
    }
#undef BAR
#undef LGKM0
#undef VMC4
#undef VMC0
}

// ---------------- softmax over T per batch --------------------------------
__global__ __launch_bounds__(256) void k_softmax(
        const float* __restrict__ e_part, float* __restrict__ a_out) {
    const int b = blockIdx.x, tid = threadIdx.x;
    const int lane = tid & 63, w = tid >> 6;
    __shared__ float red[4], red2[4];

    float ls[8];
    float lmax = -1e30f;
#pragma unroll
    for (int i = 0; i < 8; ++i) {
        size_t mm = (size_t)b * T_ + i * 256 + tid;
        float sv = 0.f;
#pragma unroll
        for (int p = 0; p < 8; ++p) sv += e_part[(size_t)p * M_ + mm];
        ls[i] = sv;
        lmax = fmaxf(lmax, sv);
    }
#pragma unroll
    for (int mm = 1; mm < 64; mm <<= 1) lmax = fmaxf(lmax, __shfl_xor(lmax, mm, 64));
    if (lane == 0) red[w] = lmax;
    __syncthreads();
    float bmax = fmaxf(fmaxf(red[0], red[1]), fmaxf(red[2], red[3]));

    float lsum = 0.f;
#pragma unroll
    for (int i = 0; i < 8; ++i) { ls[i] = __expf(ls[i] - bmax); lsum += ls[i]; }
#pragma unroll
    for (int mm = 1; mm < 64; mm <<= 1) lsum += __shfl_xor(lsum, mm, 64);
    if (lane == 0) red2[w] = lsum;
    __syncthreads();
    float inv = 1.0f / (red2[0] + red2[1] + red2[2] + red2[3]);

#pragma unroll
    for (int i = 0; i < 8; ++i)
        a_out[(size_t)b * T_ + i * 256 + tid] = ls[i] * inv;
}

// ---------------- context partials: c_part[tc][b][e], tc-chunk = 128 ------
__global__ __launch_bounds__(256) void k_ctx_part(
        const float* __restrict__ h, const float* __restrict__ a,
        float* __restrict__ c_part) {
    const int b = blockIdx.x, tc = blockIdx.y, tid = threadIdx.x;
    __shared__ float alds[128];
    if (tid < 128)
        alds[tid] = a[(size_t)b * T_ + tc * 128 + tid];
    __syncthreads();

    float4 acc = {0.f, 0.f, 0.f, 0.f};
    const float* hb = h + ((size_t)b * T_ + (size_t)tc * 128) * ENC_ + tid * 4;
    for (int t = 0; t < 128; ++t) {
        float av = alds[t];
        float4 hv = *(const float4*)(hb + (size_t)t * ENC_);
        acc.x = fmaf(av, hv.x, acc.x);
        acc.y = fmaf(av, hv.y, acc.y);
        acc.z = fmaf(av, hv.z, acc.z);
        acc.w = fmaf(av, hv.w, acc.w);
    }
    *(float4*)&c_part[((size_t)(tc * 64 + b)) * ENC_ + tid * 4] = acc;
}

// ---------------- final context reduce ------------------------------------
__global__ __launch_bounds__(256) void k_ctx_final(
        const float* __restrict__ c_part, float* __restrict__ c_out) {
    int idx = blockIdx.x * 256 + threadIdx.x;   // 16384 threads
    int off = idx * 4;
    float4 sv = {0.f, 0.f, 0.f, 0.f};
#pragma unroll
    for (int tc = 0; tc < 16; ++tc) {
        float4 v = *(const float4*)&c_part[(size_t)tc * 64 * 1024 + off];
        sv.x += v.x; sv.y += v.y; sv.z += v.z; sv.w += v.w;
    }
    *(float4*)&c_out[off] = sv;
}

extern "C" void kernel_launch(void* const* d_in, const int* in_sizes, int n_in,
                              void* d_out, int out_size, void* d_ws, size_t ws_size,
                              hipStream_t stream) {
    const float* h = (const float*)d_in[0];
    const float* s = (const float*)d_in[1];
    const float* U = (const float*)d_in[2];
    const float* W = (const float*)d_in[3];
    const float* V = (const float*)d_in[4];

    float* out   = (float*)d_out;
    float* c_out = out;                         // [64][1][1024] -> 65536 floats
    float* a_out = out + 64 * 1024;             // [64][2048][1] -> 131072 floats

    char* ws = (char*)d_ws;
    u16*   Ut     = (u16*)ws;                                       // 1 MB
    float* f2     = (float*)(ws + (1 << 20));                       // 128 KB
    float* e_part = (float*)(ws + (1 << 20) + (128 << 10));         // 4 MB
    float* c_part = e_part;   // overlay: e_part dead after k_softmax

    k_transpose_U<<<2048, 256, 0, stream>>>(U, Ut);
    k_f2<<<64, 256, 0, stream>>>(s, W, f2);

    k_gemm_e<<<4096, 256, 0, stream>>>(h, Ut, f2, V, e_part);

    k_softmax<<<64, 256, 0, stream>>>(e_part, a_out);

    dim3 gc(64, 16);
    k_ctx_part<<<gc, 256, 0, stream>>>(h, a_out, c_part);
    k_ctx_final<<<64, 256, 0, stream>>>(c_part, c_out);
}

// Round 12
// 422.397 us; speedup vs baseline: 1.2346x; 1.2346x over previous
//
#include <hip/hip_runtime.h>
#include <hip/hip_bf16.h>
#include <stdint.h>

#define B_   64
#define T_   2048
#define ENC_ 1024
#define DEC_ 1024
#define A_   512
#define M_   (B_ * T_)   // 131072

#define BM 128
#define BN 256
#define BK 64
#define NT (ENC_ / BK)   // 16 K-tiles

typedef __bf16 bf16x8 __attribute__((ext_vector_type(8)));
typedef float  f32x4  __attribute__((ext_vector_type(4)));
typedef unsigned short u16;
typedef u16 u16x8 __attribute__((ext_vector_type(8)));

__device__ __forceinline__ float fast_tanh(float x) {
    float ax = fabsf(x);
    float e  = __expf(-2.0f * ax);     // in (0,1]
    float t  = (1.0f - e) / (1.0f + e);
    return copysignf(t, x);
}

// ---------------- U transpose + convert: Ut[n][k] = bf16(U[k][n]) ----------
__global__ __launch_bounds__(256) void k_transpose_U(
        const float* __restrict__ U, u16* __restrict__ Ut) {
    int idx = blockIdx.x * 256 + threadIdx.x;     // over 1024*512
    if (idx >= ENC_ * A_) return;
    int k = idx / A_, n = idx % A_;
    __bf16 v = (__bf16)U[idx];
    Ut[n * ENC_ + k] = *(u16*)&v;
}

// ---------------- f2[b][a] = sum_e s[b][e] * W[e][a]  (fp32) ---------------
__global__ __launch_bounds__(256) void k_f2(
        const float* __restrict__ s, const float* __restrict__ W,
        float* __restrict__ f2) {
    int b = blockIdx.x;
    int a0 = threadIdx.x;
    const float* srow = s + (size_t)b * DEC_;
    float acc0 = 0.f, acc1 = 0.f;
    for (int e = 0; e < DEC_; ++e) {
        float sv = srow[e];
        acc0 = fmaf(sv, W[(size_t)e * A_ + a0],       acc0);
        acc1 = fmaf(sv, W[(size_t)e * A_ + a0 + 256], acc1);
    }
    f2[(size_t)b * A_ + a0]       = acc0;
    f2[(size_t)b * A_ + a0 + 256] = acc1;
}

// ---------------- fused GEMM + tanh + dot(V): partial e --------------------
// R7 structure (proven 2 blocks/CU) + B staged ONE TILE AHEAD:
//   A: single 16KB LDS, reg-staged bf16, swizzled ds_write (R7-identical).
//   B: DOUBLE-buffered 2x32KB, gload_lds w/ pre-swizzled source; B(t+1)
//      issued at top of tile t, consumed in t+1 -> full-tile latency hiding.
// Issue order per tile: loadA(t+1) [older] then stageB(t+1) [newer], so
// writeA's implicit reg-wait = vmcnt(4) (B keeps flying); VMC(8) before
// compute drains only B(t). vmcnt never 0 in steady state (T4).
// LDS 80KB = exactly 2 blocks/CU at launch_bounds(512,4).
__global__ __launch_bounds__(512, 4) void k_gemm_e(
        const float* __restrict__ h, const u16* __restrict__ Ut,
        const float* __restrict__ f2, const float* __restrict__ V,
        float* __restrict__ e_part) {
    __shared__ u16 Alds[BM * BK];      // 16 KB, swizzled
    __shared__ u16 Bb[2][BN * BK];     // 2 x 32 KB, swizzled

    const int tid  = threadIdx.x;
    const int lane = tid & 63;
    const int wid  = tid >> 6;         // 0..7
    const int wr   = wid >> 2;         // 0..1
    const int wc   = wid & 3;          // 0..3
    const int lr   = lane & 15;
    const int g    = lane >> 4;
    const int sw   = (lr & 7) << 3;    // read-side XOR (u16 units)

    // XCD-aware remap: column-pair adjacent on one XCD (A-panel L2/L3 reuse).
    const int d    = blockIdx.x;
    const int xcd  = d & 7;
    const int s    = d >> 3;           // 0..255 per XCD
    const int m    = s & 1;
    const int pair = xcd * 128 + (s >> 1);   // 0..1023
    const int brow = pair * BM;
    const int bcol = m * BN;
    const int b    = brow / T_;        // uniform per block (T_ % BM == 0)

    f32x4 acc[4][4] = {};              // 64 f32 -> AGPRs
    f32x4 ar[4];                       // in-flight A (fp32), 16 regs

    auto loadA = [&](int kt) {
        int flat0 = tid * 8;                       // logical u16 index
        int r = flat0 >> 6, c = flat0 & 63;
        const float* srcA = h + (size_t)(brow + r) * ENC_ + kt * BK + c;
        ar[0] = *(const f32x4*)srcA;
        ar[1] = *(const f32x4*)(srcA + 4);
        const float* srcB = srcA + (size_t)64 * ENC_;   // rows r+64
        ar[2] = *(const f32x4*)srcB;
        ar[3] = *(const f32x4*)(srcB + 4);
    };
    auto writeA = [&]() {
#pragma unroll
        for (int it = 0; it < 2; ++it) {
            int flat = (it * 512 + tid) * 8;
            int r = flat >> 6;
            u16x8 w;
#pragma unroll
            for (int j = 0; j < 4; ++j) {
                __bf16 lo = (__bf16)ar[it * 2][j], hi = (__bf16)ar[it * 2 + 1][j];
                w[j]     = *(u16*)&lo;
                w[j + 4] = *(u16*)&hi;
            }
            *(u16x8*)&Alds[flat ^ ((r & 7) << 3)] = w;
        }
    };
    auto stageB = [&](u16* Bd, int kt) {
#pragma unroll
        for (int it = 0; it < 4; ++it) {
            int G  = it * 512 + tid;                  // 16B granule index
            int n  = G >> 3;
            int kc = ((G & 7) ^ (n & 7)) << 3;        // swizzled k-offset
            const u16* src = Ut + (size_t)(bcol + n) * ENC_ + kt * BK + kc;
            u16* dst = &Bd[(size_t)(it * 512 + wid * 64) * 8];
            __builtin_amdgcn_global_load_lds(
                (const __attribute__((address_space(1))) void*)src,
                (__attribute__((address_space(3))) void*)dst, 16, 0, 0);
        }
    };
    auto compute = [&](const u16* Bc) {
#pragma unroll
        for (int kk = 0; kk < 2; ++kk) {
            bf16x8 af[4], bfr[4];
#pragma unroll
            for (int mf = 0; mf < 4; ++mf)
                af[mf] = *(const bf16x8*)&Alds[
                    (((wr * 64 + mf * 16 + lr) * 64) + kk * 32 + g * 8) ^ sw];
#pragma unroll
            for (int nf = 0; nf < 4; ++nf)
                bfr[nf] = *(const bf16x8*)&Bc[
                    (((wc * 64 + nf * 16 + lr) * 64) + kk * 32 + g * 8) ^ sw];
#pragma unroll
            for (int mf = 0; mf < 4; ++mf)
#pragma unroll
                for (int nf = 0; nf < 4; ++nf)
                    acc[mf][nf] = __builtin_amdgcn_mfma_f32_16x16x32_bf16(
                        af[mf], bfr[nf], acc[mf][nf], 0, 0, 0);
        }
    };

#define BAR()   __builtin_amdgcn_s_barrier()
#define LGKM0() asm volatile("s_waitcnt lgkmcnt(0)" ::: "memory")
#define VMC8()  asm volatile("s_waitcnt vmcnt(8)" ::: "memory")
#define VMC0()  asm volatile("s_waitcnt vmcnt(0)" ::: "memory")

    // ---- prologue: A(0)->regs, B(0) staged; writeA waits A(0) only ----
    loadA(0);                 // 4 loads (oldest)
    stageB(Bb[0], 0);         // 4 gload_lds (newer)
    writeA();                 // implicit vmcnt(4): A(0) done, B(0) flying
    LGKM0(); BAR();

    for (int t = 0; t < NT; ++t) {
        const int cur = t & 1;
        if (t + 1 < NT) {
            loadA(t + 1);                    // 4 loads (older)
            stageB(Bb[cur ^ 1], t + 1);      // 4 gload_lds (newer)
            VMC8();                          // drain B(t) only; 8 new fly
        } else {
            VMC0();                          // last tile: drain B(t)
        }
        compute(Bb[cur]);
        BAR();                               // all waves done reading Alds
        if (t + 1 < NT) {
            writeA();                        // implicit vmcnt(4): A(t+1) done
            LGKM0(); BAR();
        }
    }

    // ---- epilogue: e_partial[m] = sum_n tanh(acc + f2) * V ----
    float vv[4], ff[4];
#pragma unroll
    for (int nf = 0; nf < 4; ++nf) {
        int n = bcol + wc * 64 + nf * 16 + lr;
        vv[nf] = V[n];
        ff[nf] = f2[(size_t)b * A_ + n];
    }
    const int p = m * 4 + wc;                     // 8 partial slices
    float* ep = e_part + (size_t)p * M_ + brow + wr * 64;
#pragma unroll
    for (int mf = 0; mf < 4; ++mf) {
        float sums[4];
#pragma unroll
        for (int i = 0; i < 4; ++i) {
            float sv = 0.f;
#pragma unroll
            for (int nf = 0; nf < 4; ++nf) {
                float x = acc[mf][nf][i] + ff[nf];
                sv = fmaf(fast_tanh(x), vv[nf], sv);
            }
#pragma unroll
            for (int mm = 1; mm < 16; mm <<= 1)
                sv += __shfl_xor(sv, mm, 64);     // reduce 16 cols
            sums[i] = sv;
        }
        if (lr == 0) {
#pragma unroll
            for (int i = 0; i < 4; ++i)
                ep[mf * 16 + g * 4 + i] = sums[i];
        }
    }
#undef BAR
#undef LGKM0
#undef VMC8
#undef VMC0
}

// ---------------- softmax over T per batch --------------------------------
__global__ __launch_bounds__(256) void k_softmax(
        const float* __restrict__ e_part, float* __restrict__ a_out) {
    const int b = blockIdx.x, tid = threadIdx.x;
    const int lane = tid & 63, w = tid >> 6;
    __shared__ float red[4], red2[4];

    float ls[8];
    float lmax = -1e30f;
#pragma unroll
    for (int i = 0; i < 8; ++i) {
        size_t mm = (size_t)b * T_ + i * 256 + tid;
        float sv = 0.f;
#pragma unroll
        for (int p = 0; p < 8; ++p) sv += e_part[(size_t)p * M_ + mm];
        ls[i] = sv;
        lmax = fmaxf(lmax, sv);
    }
#pragma unroll
    for (int mm = 1; mm < 64; mm <<= 1) lmax = fmaxf(lmax, __shfl_xor(lmax, mm, 64));
    if (lane == 0) red[w] = lmax;
    __syncthreads();
    float bmax = fmaxf(fmaxf(red[0], red[1]), fmaxf(red[2], red[3]));

    float lsum = 0.f;
#pragma unroll
    for (int i = 0; i < 8; ++i) { ls[i] = __expf(ls[i] - bmax); lsum += ls[i]; }
#pragma unroll
    for (int mm = 1; mm < 64; mm <<= 1) lsum += __shfl_xor(lsum, mm, 64);
    if (lane == 0) red2[w] = lsum;
    __syncthreads();
    float inv = 1.0f / (red2[0] + red2[1] + red2[2] + red2[3]);

#pragma unroll
    for (int i = 0; i < 8; ++i)
        a_out[(size_t)b * T_ + i * 256 + tid] = ls[i] * inv;
}

// ---------------- context partials: c_part[tc][b][e], tc-chunk = 128 ------
__global__ __launch_bounds__(256) void k_ctx_part(
        const float* __restrict__ h, const float* __restrict__ a,
        float* __restrict__ c_part) {
    const int b = blockIdx.x, tc = blockIdx.y, tid = threadIdx.x;
    __shared__ float alds[128];
    if (tid < 128)
        alds[tid] = a[(size_t)b * T_ + tc * 128 + tid];
    __syncthreads();

    float4 acc = {0.f, 0.f, 0.f, 0.f};
    const float* hb = h + ((size_t)b * T_ + (size_t)tc * 128) * ENC_ + tid * 4;
    for (int t = 0; t < 128; ++t) {
        float av = alds[t];
        float4 hv = *(const float4*)(hb + (size_t)t * ENC_);
        acc.x = fmaf(av, hv.x, acc.x);
        acc.y = fmaf(av, hv.y, acc.y);
        acc.z = fmaf(av, hv.z, acc.z);
        acc.w = fmaf(av, hv.w, acc.w);
    }
    *(float4*)&c_part[((size_t)(tc * 64 + b)) * ENC_ + tid * 4] = acc;
}

// ---------------- final context reduce ------------------------------------
__global__ __launch_bounds__(256) void k_ctx_final(
        const float* __restrict__ c_part, float* __restrict__ c_out) {
    int idx = blockIdx.x * 256 + threadIdx.x;   // 16384 threads
    int off = idx * 4;
    float4 sv = {0.f, 0.f, 0.f, 0.f};
#pragma unroll
    for (int tc = 0; tc < 16; ++tc) {
        float4 v = *(const float4*)&c_part[(size_t)tc * 64 * 1024 + off];
        sv.x += v.x; sv.y += v.y; sv.z += v.z; sv.w += v.w;
    }
    *(float4*)&c_out[off] = sv;
}

extern "C" void kernel_launch(void* const* d_in, const int* in_sizes, int n_in,
                              void* d_out, int out_size, void* d_ws, size_t ws_size,
                              hipStream_t stream) {
    const float* h = (const float*)d_in[0];
    const float* s = (const float*)d_in[1];
    const float* U = (const float*)d_in[2];
    const float* W = (const float*)d_in[3];
    const float* V = (const float*)d_in[4];

    float* out   = (float*)d_out;
    float* c_out = out;                         // [64][1][1024] -> 65536 floats
    float* a_out = out + 64 * 1024;             // [64][2048][1] -> 131072 floats

    char* ws = (char*)d_ws;
    u16*   Ut     = (u16*)ws;                                       // 1 MB
    float* f2     = (float*)(ws + (1 << 20));                       // 128 KB
    float* e_part = (float*)(ws + (1 << 20) + (128 << 10));         // 4 MB
    float* c_part = e_part;   // overlay: e_part dead after k_softmax

    k_transpose_U<<<2048, 256, 0, stream>>>(U, Ut);
    k_f2<<<64, 256, 0, stream>>>(s, W, f2);

    k_gemm_e<<<2048, 512, 0, stream>>>(h, Ut, f2, V, e_part);

    k_softmax<<<64, 256, 0, stream>>>(e_part, a_out);

    dim3 gc(64, 16);
    k_ctx_part<<<gc, 256, 0, stream>>>(h, a_out, c_part);
    k_ctx_final<<<64, 256, 0, stream>>>(c_part, c_out);
}

// Round 13
// 322.594 us; speedup vs baseline: 1.6165x; 1.3094x over previous
//
#include <hip/hip_runtime.h>
#include <hip/hip_bf16.h>
#include <stdint.h>

#define B_   64
#define T_   2048
#define ENC_ 1024
#define DEC_ 1024
#define A_   512
#define M_   (B_ * T_)   // 131072

#define BK   64
#define CH   64          // fused-kernel row chunk
#define NCH  (M_ / CH)   // 2048 chunks
#define CPB  (T_ / CH)   // 32 chunks per batch

typedef __bf16 bf16x8 __attribute__((ext_vector_type(8)));
typedef float  f32x4  __attribute__((ext_vector_type(4)));
typedef unsigned short u16;
typedef u16 u16x8 __attribute__((ext_vector_type(8)));

__device__ __forceinline__ float fast_tanh(float x) {
    float ax = fabsf(x);
    float e  = __expf(-2.0f * ax);     // in (0,1]
    float t  = (1.0f - e) / (1.0f + e);
    return copysignf(t, x);
}

// ---------------- U transpose + convert: Ut[n][k] = bf16(U[k][n]) ----------
__global__ __launch_bounds__(256) void k_transpose_U(
        const float* __restrict__ U, u16* __restrict__ Ut) {
    int idx = blockIdx.x * 256 + threadIdx.x;     // over 1024*512
    if (idx >= ENC_ * A_) return;
    int k = idx / A_, n = idx % A_;
    __bf16 v = (__bf16)U[idx];
    Ut[n * ENC_ + k] = *(u16*)&v;
}

// ---------------- f2[b][a] = sum_e s[b][e] * W[e][a]  (fp32) ---------------
__global__ __launch_bounds__(256) void k_f2(
        const float* __restrict__ s, const float* __restrict__ W,
        float* __restrict__ f2) {
    int b = blockIdx.x;
    int a0 = threadIdx.x;
    const float* srow = s + (size_t)b * DEC_;
    float acc0 = 0.f, acc1 = 0.f;
    for (int e = 0; e < DEC_; ++e) {
        float sv = srow[e];
        acc0 = fmaf(sv, W[(size_t)e * A_ + a0],       acc0);
        acc1 = fmaf(sv, W[(size_t)e * A_ + a0 + 256], acc1);
    }
    f2[(size_t)b * A_ + a0]       = acc0;
    f2[(size_t)b * A_ + a0 + 256] = acc1;
}

// ========== FUSED: GEMM + tanh·V -> e ; online-softmax ctx partials =======
// One block = 64 rows x FULL A=512 (so the block owns complete e rows).
// 512 threads, 8 waves 1x8, wave tile 64x64 (acc = 64 AGPR). R7's proven
// staging: B[512x64] via gload_lds pre-swizzled source (64KB), A[64x64]
// reg-staged bf16 swizzled ds_write (8KB), 2 barriers/K-tile, 2 blocks/CU.
// Epilogue: partial e per wave -> LDS -> wave0 reduces (m_b, s_b, w_r) ->
// all threads accumulate o[1024] over the 64 rows (h re-read, L2/L3-warm)
// -> per-chunk partials (o, m, s). h touches HBM ONCE for the whole op.
__global__ __launch_bounds__(512, 4) void k_gemm_fused(
        const float* __restrict__ h, const u16* __restrict__ Ut,
        const float* __restrict__ f2, const float* __restrict__ V,
        float* __restrict__ e_full, float* __restrict__ mpart,
        float* __restrict__ spart, float* __restrict__ opart) {
    __shared__ u16 Alds[CH * BK];      // 8 KB, swizzled
    __shared__ u16 Blds[A_ * BK];      // 64 KB, swizzled
    __shared__ float ered[8][64];      // per-wave partial e
    __shared__ float wlds[64];         // exp(e - m_b) weights

    const int tid  = threadIdx.x;
    const int lane = tid & 63;
    const int wid  = tid >> 6;         // 0..7 = wave col-slice
    const int lr   = lane & 15;
    const int g    = lane >> 4;
    const int sw   = (lr & 7) << 3;    // read-side XOR (u16 units)

    // XCD remap: each XCD gets 256 contiguous chunks (= 8 whole batches).
    const int d      = blockIdx.x;     // 0..2047
    const int gchunk = (d & 7) * 256 + (d >> 3);
    const int brow   = gchunk * CH;
    const int b      = gchunk >> 5;    // gchunk / CPB
    const int chunk  = gchunk & 31;

    f32x4 acc[4][4] = {};              // 64 f32 -> AGPRs

    for (int kt = 0; kt < ENC_ / BK; ++kt) {
        const int k0 = kt * BK;
        // ---- stage B: 8 gload_lds, LINEAR dest + pre-swizzled SOURCE ----
#pragma unroll
        for (int it = 0; it < 8; ++it) {
            int G  = it * 512 + tid;                  // 16B granule index
            int n  = G >> 3;
            int kc = ((G & 7) ^ (n & 7)) << 3;        // swizzled k-offset
            const u16* src = Ut + (size_t)n * ENC_ + k0 + kc;
            u16* dst = &Blds[(size_t)(it * 512 + wid * 64) * 8];
            __builtin_amdgcn_global_load_lds(
                (const __attribute__((address_space(1))) void*)src,
                (__attribute__((address_space(3))) void*)dst, 16, 0, 0);
        }
        // ---- stage A: fp32 -> bf16 via regs, swizzled ds_write ----
        {
            int r = tid >> 3, c = (tid & 7) * 8;
            const float* srcA = h + (size_t)(brow + r) * ENC_ + k0 + c;
            f32x4 v0 = *(const f32x4*)srcA;
            f32x4 v1 = *(const f32x4*)(srcA + 4);
            u16x8 w;
#pragma unroll
            for (int j = 0; j < 4; ++j) {
                __bf16 lo = (__bf16)v0[j], hi = (__bf16)v1[j];
                w[j]     = *(u16*)&lo;
                w[j + 4] = *(u16*)&hi;
            }
            *(u16x8*)&Alds[(tid * 8) ^ ((r & 7) << 3)] = w;
        }
        __syncthreads();

#pragma unroll
        for (int kk = 0; kk < 2; ++kk) {
            bf16x8 af[4], bfr[4];
#pragma unroll
            for (int mf = 0; mf < 4; ++mf)
                af[mf] = *(const bf16x8*)&Alds[
                    (((mf * 16 + lr) * 64) + kk * 32 + g * 8) ^ sw];
#pragma unroll
            for (int nf = 0; nf < 4; ++nf)
                bfr[nf] = *(const bf16x8*)&Blds[
                    (((wid * 64 + nf * 16 + lr) * 64) + kk * 32 + g * 8) ^ sw];
#pragma unroll
            for (int mf = 0; mf < 4; ++mf)
#pragma unroll
                for (int nf = 0; nf < 4; ++nf)
                    acc[mf][nf] = __builtin_amdgcn_mfma_f32_16x16x32_bf16(
                        af[mf], bfr[nf], acc[mf][nf], 0, 0, 0);
        }
        __syncthreads();
    }

    // ---- epilogue A: per-wave partial e over its 64-col slice ----
    float vv[4], ff[4];
#pragma unroll
    for (int nf = 0; nf < 4; ++nf) {
        int n = wid * 64 + nf * 16 + lr;
        vv[nf] = V[n];
        ff[nf] = f2[(size_t)b * A_ + n];
    }
#pragma unroll
    for (int mf = 0; mf < 4; ++mf) {
        float sums[4];
#pragma unroll
        for (int i = 0; i < 4; ++i) {
            float sv = 0.f;
#pragma unroll
            for (int nf = 0; nf < 4; ++nf) {
                float x = acc[mf][nf][i] + ff[nf];
                sv = fmaf(fast_tanh(x), vv[nf], sv);
            }
#pragma unroll
            for (int mm = 1; mm < 16; mm <<= 1)
                sv += __shfl_xor(sv, mm, 64);     // reduce 16 cols
            sums[i] = sv;
        }
        if (lr == 0) {
#pragma unroll
            for (int i = 0; i < 4; ++i)
                ered[wid][mf * 16 + g * 4 + i] = sums[i];
        }
    }
    __syncthreads();

    // ---- epilogue B: wave 0 reduces 8 slices -> e row, m_b, s_b, w_r ----
    if (tid < 64) {
        float er = 0.f;
#pragma unroll
        for (int w = 0; w < 8; ++w) er += ered[w][tid];
        float mb = er;
#pragma unroll
        for (int mm = 1; mm < 64; mm <<= 1)
            mb = fmaxf(mb, __shfl_xor(mb, mm, 64));
        float wr_ = __expf(er - mb);
        float sb = wr_;
#pragma unroll
        for (int mm = 1; mm < 64; mm <<= 1)
            sb += __shfl_xor(sb, mm, 64);
        wlds[tid] = wr_;
        e_full[(size_t)b * T_ + chunk * CH + tid] = er;   // RAW e
        if (tid == 0) { mpart[gchunk] = mb; spart[gchunk] = sb; }
    }
    __syncthreads();

    // ---- epilogue C: o[col] = sum_r w_r * h[r][col]  (h is L2/L3-warm) ----
    const int c2 = tid * 2;
    float o0 = 0.f, o1 = 0.f;
#pragma unroll 8
    for (int r = 0; r < CH; ++r) {
        float w = wlds[r];                      // broadcast (free)
        float2 hv = *(const float2*)(h + (size_t)(brow + r) * ENC_ + c2);
        o0 = fmaf(w, hv.x, o0);
        o1 = fmaf(w, hv.y, o1);
    }
    float* op = opart + (size_t)gchunk * ENC_ + c2;
    op[0] = o0; op[1] = o1;
}

// ---------------- per-batch flash-merge of 32 chunk partials --------------
__global__ __launch_bounds__(256) void k_ctx_reduce(
        const float* __restrict__ mpart, const float* __restrict__ spart,
        const float* __restrict__ opart, float* __restrict__ c_out,
        float* __restrict__ mg_g, float* __restrict__ sg_g) {
    const int b = blockIdx.x, tid = threadIdx.x;
    __shared__ float esc[CPB];
    __shared__ float mgS, sgS;

    if (tid < CPB) {                       // lanes 0..31 of wave 0
        float mr = mpart[b * CPB + tid];
        float sr = spart[b * CPB + tid];
        float mg = mr;
#pragma unroll
        for (int mm = 1; mm < 32; mm <<= 1)
            mg = fmaxf(mg, __shfl_xor(mg, mm, 32));
        float e = __expf(mr - mg);
        esc[tid] = e;
        float S = sr * e;
#pragma unroll
        for (int mm = 1; mm < 32; mm <<= 1)
            S += __shfl_xor(S, mm, 32);
        if (tid == 0) { mgS = mg; sgS = S; mg_g[b] = mg; sg_g[b] = S; }
    }
    __syncthreads();
    float inv = 1.0f / sgS;
    int c = tid * 4;                       // 1024 cols / 256 threads
    f32x4 av = {0.f, 0.f, 0.f, 0.f};
    for (int r = 0; r < CPB; ++r) {
        f32x4 ov = *(const f32x4*)&opart[((size_t)(b * CPB + r)) * ENC_ + c];
        float e = esc[r];
        av[0] = fmaf(e, ov[0], av[0]); av[1] = fmaf(e, ov[1], av[1]);
        av[2] = fmaf(e, ov[2], av[2]); av[3] = fmaf(e, ov[3], av[3]);
    }
    av[0] *= inv; av[1] *= inv; av[2] *= inv; av[3] *= inv;
    *(f32x4*)&c_out[(size_t)b * ENC_ + c] = av;
}

// ---------------- a = exp(e - m_g) / S_g ----------------------------------
__global__ __launch_bounds__(256) void k_a_final(
        const float* __restrict__ e_full, const float* __restrict__ mg_g,
        const float* __restrict__ sg_g, float* __restrict__ a_out) {
    int idx = blockIdx.x * 256 + threadIdx.x;   // over M_
    int b = idx >> 11;                          // T_ = 2048
    a_out[idx] = __expf(e_full[idx] - mg_g[b]) / sg_g[b];
}

// ================= fallback path (ws too small): R7 kernels ================
__global__ __launch_bounds__(512, 4) void k_gemm_e_fb(
        const float* __restrict__ h, const u16* __restrict__ Ut,
        const float* __restrict__ f2, const float* __restrict__ V,
        float* __restrict__ e_part) {
    __shared__ u16 Alds[128 * BK];
    __shared__ u16 Blds[256 * BK];
    const int tid = threadIdx.x, lane = tid & 63, wid = tid >> 6;
    const int wr = wid >> 2, wc = wid & 3, lr = lane & 15, g = lane >> 4;
    const int sw = (lr & 7) << 3;
    const int d = blockIdx.x, xcd = d & 7, s = d >> 3, m = s & 1;
    const int pair = xcd * 128 + (s >> 1);
    const int brow = pair * 128, bcol = m * 256, b = brow / T_;
    f32x4 acc[4][4] = {};
    for (int kt = 0; kt < ENC_ / BK; ++kt) {
        const int k0 = kt * BK;
#pragma unroll
        for (int it = 0; it < 4; ++it) {
            int G = it * 512 + tid, n = G >> 3;
            int kc = ((G & 7) ^ (n & 7)) << 3;
            const u16* src = Ut + (size_t)(bcol + n) * ENC_ + k0 + kc;
            u16* dst = &Blds[(size_t)(it * 512 + wid * 64) * 8];
            __builtin_amdgcn_global_load_lds(
                (const __attribute__((address_space(1))) void*)src,
                (__attribute__((address_space(3))) void*)dst, 16, 0, 0);
        }
#pragma unroll
        for (int it = 0; it < 2; ++it) {
            int flat = (it * 512 + tid) * 8, r = flat >> 6, c = flat & 63;
            const float* srcA = h + (size_t)(brow + r) * ENC_ + k0 + c;
            f32x4 v0 = *(const f32x4*)srcA, v1 = *(const f32x4*)(srcA + 4);
            u16x8 w;
#pragma unroll
            for (int j = 0; j < 4; ++j) {
                __bf16 lo = (__bf16)v0[j], hi = (__bf16)v1[j];
                w[j] = *(u16*)&lo; w[j + 4] = *(u16*)&hi;
            }
            *(u16x8*)&Alds[flat ^ ((r & 7) << 3)] = w;
        }
        __syncthreads();
#pragma unroll
        for (int kk = 0; kk < 2; ++kk) {
            bf16x8 af[4], bfr[4];
#pragma unroll
            for (int mf = 0; mf < 4; ++mf)
                af[mf] = *(const bf16x8*)&Alds[(((wr * 64 + mf * 16 + lr) * 64) + kk * 32 + g * 8) ^ sw];
#pragma unroll
            for (int nf = 0; nf < 4; ++nf)
                bfr[nf] = *(const bf16x8*)&Blds[(((wc * 64 + nf * 16 + lr) * 64) + kk * 32 + g * 8) ^ sw];
#pragma unroll
            for (int mf = 0; mf < 4; ++mf)
#pragma unroll
                for (int nf = 0; nf < 4; ++nf)
                    acc[mf][nf] = __builtin_amdgcn_mfma_f32_16x16x32_bf16(
                        af[mf], bfr[nf], acc[mf][nf], 0, 0, 0);
        }
        __syncthreads();
    }
    float vv[4], ff[4];
#pragma unroll
    for (int nf = 0; nf < 4; ++nf) {
        int n = bcol + wc * 64 + nf * 16 + lr;
        vv[nf] = V[n]; ff[nf] = f2[(size_t)b * A_ + n];
    }
    const int p = m * 4 + wc;
    float* ep = e_part + (size_t)p * M_ + brow + wr * 64;
#pragma unroll
    for (int mf = 0; mf < 4; ++mf) {
        float sums[4];
#pragma unroll
        for (int i = 0; i < 4; ++i) {
            float sv = 0.f;
#pragma unroll
            for (int nf = 0; nf < 4; ++nf)
                sv = fmaf(fast_tanh(acc[mf][nf][i] + ff[nf]), vv[nf], sv);
#pragma unroll
            for (int mm = 1; mm < 16; mm <<= 1) sv += __shfl_xor(sv, mm, 64);
            sums[i] = sv;
        }
        if (lr == 0)
#pragma unroll
            for (int i = 0; i < 4; ++i) ep[mf * 16 + g * 4 + i] = sums[i];
    }
}

__global__ __launch_bounds__(256) void k_softmax_fb(
        const float* __restrict__ e_part, float* __restrict__ a_out) {
    const int b = blockIdx.x, tid = threadIdx.x;
    const int lane = tid & 63, w = tid >> 6;
    __shared__ float red[4], red2[4];
    float ls[8]; float lmax = -1e30f;
#pragma unroll
    for (int i = 0; i < 8; ++i) {
        size_t mm = (size_t)b * T_ + i * 256 + tid;
        float sv = 0.f;
#pragma unroll
        for (int p = 0; p < 8; ++p) sv += e_part[(size_t)p * M_ + mm];
        ls[i] = sv; lmax = fmaxf(lmax, sv);
    }
#pragma unroll
    for (int mm = 1; mm < 64; mm <<= 1) lmax = fmaxf(lmax, __shfl_xor(lmax, mm, 64));
    if (lane == 0) red[w] = lmax;
    __syncthreads();
    float bmax = fmaxf(fmaxf(red[0], red[1]), fmaxf(red[2], red[3]));
    float lsum = 0.f;
#pragma unroll
    for (int i = 0; i < 8; ++i) { ls[i] = __expf(ls[i] - bmax); lsum += ls[i]; }
#pragma unroll
    for (int mm = 1; mm < 64; mm <<= 1) lsum += __shfl_xor(lsum, mm, 64);
    if (lane == 0) red2[w] = lsum;
    __syncthreads();
    float inv = 1.0f / (red2[0] + red2[1] + red2[2] + red2[3]);
#pragma unroll
    for (int i = 0; i < 8; ++i)
        a_out[(size_t)b * T_ + i * 256 + tid] = ls[i] * inv;
}

__global__ __launch_bounds__(256) void k_ctx_part_fb(
        const float* __restrict__ h, const float* __restrict__ a,
        float* __restrict__ c_part) {
    const int b = blockIdx.x, tc = blockIdx.y, tid = threadIdx.x;
    __shared__ float alds[128];
    if (tid < 128) alds[tid] = a[(size_t)b * T_ + tc * 128 + tid];
    __syncthreads();
    float4 acc = {0.f, 0.f, 0.f, 0.f};
    const float* hb = h + ((size_t)b * T_ + (size_t)tc * 128) * ENC_ + tid * 4;
    for (int t = 0; t < 128; ++t) {
        float av = alds[t];
        float4 hv = *(const float4*)(hb + (size_t)t * ENC_);
        acc.x = fmaf(av, hv.x, acc.x); acc.y = fmaf(av, hv.y, acc.y);
        acc.z = fmaf(av, hv.z, acc.z); acc.w = fmaf(av, hv.w, acc.w);
    }
    *(float4*)&c_part[((size_t)(tc * 64 + b)) * ENC_ + tid * 4] = acc;
}

__global__ __launch_bounds__(256) void k_ctx_final_fb(
        const float* __restrict__ c_part, float* __restrict__ c_out) {
    int idx = blockIdx.x * 256 + threadIdx.x;
    int off = idx * 4;
    float4 sv = {0.f, 0.f, 0.f, 0.f};
#pragma unroll
    for (int tc = 0; tc < 16; ++tc) {
        float4 v = *(const float4*)&c_part[(size_t)tc * 64 * 1024 + off];
        sv.x += v.x; sv.y += v.y; sv.z += v.z; sv.w += v.w;
    }
    *(float4*)&c_out[off] = sv;
}

extern "C" void kernel_launch(void* const* d_in, const int* in_sizes, int n_in,
                              void* d_out, int out_size, void* d_ws, size_t ws_size,
                              hipStream_t stream) {
    const float* h = (const float*)d_in[0];
    const float* s = (const float*)d_in[1];
    const float* U = (const float*)d_in[2];
    const float* W = (const float*)d_in[3];
    const float* V = (const float*)d_in[4];

    float* out   = (float*)d_out;
    float* c_out = out;                         // [64][1][1024]
    float* a_out = out + 64 * 1024;             // [64][2048][1]

    char* ws = (char*)d_ws;
    u16*   Ut = (u16*)ws;                                  // 1 MB
    float* f2 = (float*)(ws + (1 << 20));                  // 128 KB

    k_transpose_U<<<2048, 256, 0, stream>>>(U, Ut);
    k_f2<<<64, 256, 0, stream>>>(s, W, f2);

    const size_t NEED = (size_t)10 * 1024 * 1024 + (64 << 10);
    if (ws_size >= NEED) {
        float* e_full = (float*)(ws + 0x120000);           // 512 KB
        float* mpart  = (float*)(ws + 0x1A0000);           // 8 KB
        float* spart  = (float*)(ws + 0x1A2000);           // 8 KB
        float* mg_g   = (float*)(ws + 0x1A4000);           // 256 B
        float* sg_g   = (float*)(ws + 0x1A4100);           // 256 B
        float* opart  = (float*)(ws + 0x200000);           // 8 MB

        k_gemm_fused<<<NCH, 512, 0, stream>>>(h, Ut, f2, V,
                                              e_full, mpart, spart, opart);
        k_ctx_reduce<<<64, 256, 0, stream>>>(mpart, spart, opart,
                                             c_out, mg_g, sg_g);
        k_a_final<<<M_ / 256, 256, 0, stream>>>(e_full, mg_g, sg_g, a_out);
    } else {
        float* e_part = (float*)(ws + (1 << 20) + (128 << 10));  // 4 MB
        float* c_part = e_part;    // overlay after softmax
        k_gemm_e_fb<<<2048, 512, 0, stream>>>(h, Ut, f2, V, e_part);
        k_softmax_fb<<<64, 256, 0, stream>>>(e_part, a_out);
        dim3 gc(64, 16);
        k_ctx_part_fb<<<gc, 256, 0, stream>>>(h, a_out, c_part);
        k_ctx_final_fb<<<64, 256, 0, stream>>>(c_part, c_out);
    }
}

// Round 14
// 313.037 us; speedup vs baseline: 1.6659x; 1.0305x over previous
//
#include <hip/hip_runtime.h>
#include <hip/hip_bf16.h>
#include <stdint.h>

#define B_   64
#define T_   2048
#define ENC_ 1024
#define DEC_ 1024
#define A_   512
#define M_   (B_ * T_)   // 131072

#define BK   64
#define CH   64          // fused-kernel row chunk
#define NCH  (M_ / CH)   // 2048 chunks
#define CPB  (T_ / CH)   // 32 chunks per batch

typedef __bf16 bf16x8 __attribute__((ext_vector_type(8)));
typedef float  f32x4  __attribute__((ext_vector_type(4)));
typedef unsigned short u16;
typedef u16 u16x8 __attribute__((ext_vector_type(8)));

__device__ __forceinline__ float fast_tanh(float x) {
    float ax = fabsf(x);
    float e  = __expf(-2.0f * ax);     // in (0,1]
    float t  = (1.0f - e) / (1.0f + e);
    return copysignf(t, x);
}

// ---------------- U transpose + convert: Ut[n][k] = bf16(U[k][n]) ----------
__global__ __launch_bounds__(256) void k_transpose_U(
        const float* __restrict__ U, u16* __restrict__ Ut) {
    int idx = blockIdx.x * 256 + threadIdx.x;     // over 1024*512
    if (idx >= ENC_ * A_) return;
    int k = idx / A_, n = idx % A_;
    __bf16 v = (__bf16)U[idx];
    Ut[n * ENC_ + k] = *(u16*)&v;
}

// ---------------- f2[b][a] = sum_e s[b][e] * W[e][a]  (fp32) ---------------
__global__ __launch_bounds__(256) void k_f2(
        const float* __restrict__ s, const float* __restrict__ W,
        float* __restrict__ f2) {
    int b = blockIdx.x;
    int a0 = threadIdx.x;
    const float* srow = s + (size_t)b * DEC_;
    float acc0 = 0.f, acc1 = 0.f;
    for (int e = 0; e < DEC_; ++e) {
        float sv = srow[e];
        acc0 = fmaf(sv, W[(size_t)e * A_ + a0],       acc0);
        acc1 = fmaf(sv, W[(size_t)e * A_ + a0 + 256], acc1);
    }
    f2[(size_t)b * A_ + a0]       = acc0;
    f2[(size_t)b * A_ + a0 + 256] = acc1;
}

// ========== FUSED: GEMM + tanh·V -> e ; online-softmax ctx partials =======
// One block = 64 rows x FULL A=512. 512 threads, 8 waves 1x8, wave tile
// 64x64. A DOUBLE-buffered (2x8KB) with prefetch distance 1: loadA(t+1)
// issued BEFORE compute(t) (~1000 cyc slack), writeA->Alds[cur^1] right
// after compute (non-read buffer: no barrier needed; implicit vmcnt wait is
// nearly free). B single 64KB via gload_lds pre-swizzled source. 2 barriers
// per tile. LDS = 80KB exactly -> 2 blocks/CU; ered/wlds ALIAS Alds[0]
// (safe: last Alds[0] read was kt=14, fenced by that tile's two barriers;
// compute(15) touches only Alds[1]+Blds).
__global__ __launch_bounds__(512, 4) void k_gemm_fused(
        const float* __restrict__ h, const u16* __restrict__ Ut,
        const float* __restrict__ f2, const float* __restrict__ V,
        float* __restrict__ e_full, float* __restrict__ mpart,
        float* __restrict__ spart, float* __restrict__ opart) {
    __shared__ u16 Alds[2][CH * BK];   // 2 x 8 KB, swizzled
    __shared__ u16 Blds[A_ * BK];      // 64 KB, swizzled
    float* ered = (float*)&Alds[0][0]; // [8][64] alias (epilogue only)
    float* wlds = ered + 512;          // [64]    alias (epilogue only)

    const int tid  = threadIdx.x;
    const int lane = tid & 63;
    const int wid  = tid >> 6;         // 0..7 = wave col-slice
    const int lr   = lane & 15;
    const int g    = lane >> 4;
    const int sw   = (lr & 7) << 3;    // read-side XOR (u16 units)

    // XCD remap: each XCD gets 256 contiguous chunks (= 8 whole batches).
    const int d      = blockIdx.x;     // 0..2047
    const int gchunk = (d & 7) * 256 + (d >> 3);
    const int brow   = gchunk * CH;
    const int b      = gchunk >> 5;    // gchunk / CPB
    const int chunk  = gchunk & 31;

    f32x4 acc[4][4] = {};              // 64 f32 -> AGPRs
    f32x4 ar[2];                       // in-flight A (fp32), 8 regs

    const int arow = tid >> 3;
    const int acol = (tid & 7) * 8;
    auto loadA = [&](int kt) {
        const float* srcA = h + (size_t)(brow + arow) * ENC_ + kt * BK + acol;
        ar[0] = *(const f32x4*)srcA;
        ar[1] = *(const f32x4*)(srcA + 4);
    };
    auto writeA = [&](int buf) {
        u16x8 w;
#pragma unroll
        for (int j = 0; j < 4; ++j) {
            __bf16 lo = (__bf16)ar[0][j], hi = (__bf16)ar[1][j];
            w[j]     = *(u16*)&lo;
            w[j + 4] = *(u16*)&hi;
        }
        *(u16x8*)&Alds[buf][(tid * 8) ^ ((arow & 7) << 3)] = w;
    };
    auto stageB = [&](int kt) {
#pragma unroll
        for (int it = 0; it < 8; ++it) {
            int G  = it * 512 + tid;                  // 16B granule index
            int n  = G >> 3;
            int kc = ((G & 7) ^ (n & 7)) << 3;        // swizzled k-offset
            const u16* src = Ut + (size_t)n * ENC_ + kt * BK + kc;
            u16* dst = &Blds[(size_t)(it * 512 + wid * 64) * 8];
            __builtin_amdgcn_global_load_lds(
                (const __attribute__((address_space(1))) void*)src,
                (__attribute__((address_space(3))) void*)dst, 16, 0, 0);
        }
    };
    auto compute = [&](int cur) {
#pragma unroll
        for (int kk = 0; kk < 2; ++kk) {
            bf16x8 af[4], bfr[4];
#pragma unroll
            for (int mf = 0; mf < 4; ++mf)
                af[mf] = *(const bf16x8*)&Alds[cur][
                    (((mf * 16 + lr) * 64) + kk * 32 + g * 8) ^ sw];
#pragma unroll
            for (int nf = 0; nf < 4; ++nf)
                bfr[nf] = *(const bf16x8*)&Blds[
                    (((wid * 64 + nf * 16 + lr) * 64) + kk * 32 + g * 8) ^ sw];
#pragma unroll
            for (int mf = 0; mf < 4; ++mf)
#pragma unroll
                for (int nf = 0; nf < 4; ++nf)
                    acc[mf][nf] = __builtin_amdgcn_mfma_f32_16x16x32_bf16(
                        af[mf], bfr[nf], acc[mf][nf], 0, 0, 0);
        }
    };

    // ---- prologue: A(0)+B(0) staged, full drain ----
    loadA(0);
    writeA(0);                 // implicit wait on A(0) regs
    stageB(0);
    __syncthreads();           // drains B gload_lds + lgkm

    for (int kt = 0; kt < ENC_ / BK; ++kt) {
        const int cur = kt & 1;
        if (kt + 1 < ENC_ / BK) loadA(kt + 1);   // ~compute-long slack
        compute(cur);
        if (kt + 1 < ENC_ / BK) {
            writeA(cur ^ 1);   // non-read buffer; implicit vmcnt wait cheap
            __syncthreads();   // Blds readers done; ds_writes drained
            stageB(kt + 1);
            __syncthreads();   // B(kt+1) ready
        }
    }

    // ---- epilogue A: per-wave partial e over its 64-col slice ----
    float vv[4], ff[4];
#pragma unroll
    for (int nf = 0; nf < 4; ++nf) {
        int n = wid * 64 + nf * 16 + lr;
        vv[nf] = V[n];
        ff[nf] = f2[(size_t)b * A_ + n];
    }
#pragma unroll
    for (int mf = 0; mf < 4; ++mf) {
        float sums[4];
#pragma unroll
        for (int i = 0; i < 4; ++i) {
            float sv = 0.f;
#pragma unroll
            for (int nf = 0; nf < 4; ++nf) {
                float x = acc[mf][nf][i] + ff[nf];
                sv = fmaf(fast_tanh(x), vv[nf], sv);
            }
#pragma unroll
            for (int mm = 1; mm < 16; mm <<= 1)
                sv += __shfl_xor(sv, mm, 64);     // reduce 16 cols
            sums[i] = sv;
        }
        if (lr == 0) {
#pragma unroll
            for (int i = 0; i < 4; ++i)
                ered[wid * 64 + mf * 16 + g * 4 + i] = sums[i];
        }
    }
    __syncthreads();

    // ---- epilogue B: wave 0 reduces 8 slices -> e row, m_b, s_b, w_r ----
    if (tid < 64) {
        float er = 0.f;
#pragma unroll
        for (int w = 0; w < 8; ++w) er += ered[w * 64 + tid];
        float mb = er;
#pragma unroll
        for (int mm = 1; mm < 64; mm <<= 1)
            mb = fmaxf(mb, __shfl_xor(mb, mm, 64));
        float wr_ = __expf(er - mb);
        float sb = wr_;
#pragma unroll
        for (int mm = 1; mm < 64; mm <<= 1)
            sb += __shfl_xor(sb, mm, 64);
        wlds[tid] = wr_;
        e_full[(size_t)b * T_ + chunk * CH + tid] = er;   // RAW e
        if (tid == 0) { mpart[gchunk] = mb; spart[gchunk] = sb; }
    }
    __syncthreads();

    // ---- epilogue C: o[col] = sum_r w_r * h[r][col]  (h is L2/L3-warm) ----
    const int c2 = tid * 2;
    float o0 = 0.f, o1 = 0.f;
#pragma unroll 8
    for (int r = 0; r < CH; ++r) {
        float w = wlds[r];                      // broadcast (free)
        float2 hv = *(const float2*)(h + (size_t)(brow + r) * ENC_ + c2);
        o0 = fmaf(w, hv.x, o0);
        o1 = fmaf(w, hv.y, o1);
    }
    float* op = opart + (size_t)gchunk * ENC_ + c2;
    op[0] = o0; op[1] = o1;
}

// ---------------- per-batch flash-merge of 32 chunk partials --------------
__global__ __launch_bounds__(256) void k_ctx_reduce(
        const float* __restrict__ mpart, const float* __restrict__ spart,
        const float* __restrict__ opart, float* __restrict__ c_out,
        float* __restrict__ mg_g, float* __restrict__ sg_g) {
    const int b = blockIdx.x, tid = threadIdx.x;
    __shared__ float esc[CPB];
    __shared__ float mgS, sgS;

    if (tid < CPB) {                       // lanes 0..31 of wave 0
        float mr = mpart[b * CPB + tid];
        float sr = spart[b * CPB + tid];
        float mg = mr;
#pragma unroll
        for (int mm = 1; mm < 32; mm <<= 1)
            mg = fmaxf(mg, __shfl_xor(mg, mm, 32));
        float e = __expf(mr - mg);
        esc[tid] = e;
        float S = sr * e;
#pragma unroll
        for (int mm = 1; mm < 32; mm <<= 1)
            S += __shfl_xor(S, mm, 32);
        if (tid == 0) { mgS = mg; sgS = S; mg_g[b] = mg; sg_g[b] = S; }
    }
    __syncthreads();
    float inv = 1.0f / sgS;
    int c = tid * 4;                       // 1024 cols / 256 threads
    f32x4 av = {0.f, 0.f, 0.f, 0.f};
    for (int r = 0; r < CPB; ++r) {
        f32x4 ov = *(const f32x4*)&opart[((size_t)(b * CPB + r)) * ENC_ + c];
        float e = esc[r];
        av[0] = fmaf(e, ov[0], av[0]); av[1] = fmaf(e, ov[1], av[1]);
        av[2] = fmaf(e, ov[2], av[2]); av[3] = fmaf(e, ov[3], av[3]);
    }
    av[0] *= inv; av[1] *= inv; av[2] *= inv; av[3] *= inv;
    *(f32x4*)&c_out[(size_t)b * ENC_ + c] = av;
}

// ---------------- a = exp(e - m_g) / S_g ----------------------------------
__global__ __launch_bounds__(256) void k_a_final(
        const float* __restrict__ e_full, const float* __restrict__ mg_g,
        const float* __restrict__ sg_g, float* __restrict__ a_out) {
    int idx = blockIdx.x * 256 + threadIdx.x;   // over M_
    int b = idx >> 11;                          // T_ = 2048
    a_out[idx] = __expf(e_full[idx] - mg_g[b]) / sg_g[b];
}

// ================= fallback path (ws too small): R7 kernels ================
__global__ __launch_bounds__(512, 4) void k_gemm_e_fb(
        const float* __restrict__ h, const u16* __restrict__ Ut,
        const float* __restrict__ f2, const float* __restrict__ V,
        float* __restrict__ e_part) {
    __shared__ u16 Alds[128 * BK];
    __shared__ u16 Blds[256 * BK];
    const int tid = threadIdx.x, lane = tid & 63, wid = tid >> 6;
    const int wr = wid >> 2, wc = wid & 3, lr = lane & 15, g = lane >> 4;
    const int sw = (lr & 7) << 3;
    const int d = blockIdx.x, xcd = d & 7, s = d >> 3, m = s & 1;
    const int pair = xcd * 128 + (s >> 1);
    const int brow = pair * 128, bcol = m * 256, b = brow / T_;
    f32x4 acc[4][4] = {};
    for (int kt = 0; kt < ENC_ / BK; ++kt) {
        const int k0 = kt * BK;
#pragma unroll
        for (int it = 0; it < 4; ++it) {
            int G = it * 512 + tid, n = G >> 3;
            int kc = ((G & 7) ^ (n & 7)) << 3;
            const u16* src = Ut + (size_t)(bcol + n) * ENC_ + k0 + kc;
            u16* dst = &Blds[(size_t)(it * 512 + wid * 64) * 8];
            __builtin_amdgcn_global_load_lds(
                (const __attribute__((address_space(1))) void*)src,
                (__attribute__((address_space(3))) void*)dst, 16, 0, 0);
        }
#pragma unroll
        for (int it = 0; it < 2; ++it) {
            int flat = (it * 512 + tid) * 8, r = flat >> 6, c = flat & 63;
            const float* srcA = h + (size_t)(brow + r) * ENC_ + k0 + c;
            f32x4 v0 = *(const f32x4*)srcA, v1 = *(const f32x4*)(srcA + 4);
            u16x8 w;
#pragma unroll
            for (int j = 0; j < 4; ++j) {
                __bf16 lo = (__bf16)v0[j], hi = (__bf16)v1[j];
                w[j] = *(u16*)&lo; w[j + 4] = *(u16*)&hi;
            }
            *(u16x8*)&Alds[flat ^ ((r & 7) << 3)] = w;
        }
        __syncthreads();
#pragma unroll
        for (int kk = 0; kk < 2; ++kk) {
            bf16x8 af[4], bfr[4];
#pragma unroll
            for (int mf = 0; mf < 4; ++mf)
                af[mf] = *(const bf16x8*)&Alds[(((wr * 64 + mf * 16 + lr) * 64) + kk * 32 + g * 8) ^ sw];
#pragma unroll
            for (int nf = 0; nf < 4; ++nf)
                bfr[nf] = *(const bf16x8*)&Blds[(((wc * 64 + nf * 16 + lr) * 64) + kk * 32 + g * 8) ^ sw];
#pragma unroll
            for (int mf = 0; mf < 4; ++mf)
#pragma unroll
                for (int nf = 0; nf < 4; ++nf)
                    acc[mf][nf] = __builtin_amdgcn_mfma_f32_16x16x32_bf16(
                        af[mf], bfr[nf], acc[mf][nf], 0, 0, 0);
        }
        __syncthreads();
    }
    float vv[4], ff[4];
#pragma unroll
    for (int nf = 0; nf < 4; ++nf) {
        int n = bcol + wc * 64 + nf * 16 + lr;
        vv[nf] = V[n]; ff[nf] = f2[(size_t)b * A_ + n];
    }
    const int p = m * 4 + wc;
    float* ep = e_part + (size_t)p * M_ + brow + wr * 64;
#pragma unroll
    for (int mf = 0; mf < 4; ++mf) {
        float sums[4];
#pragma unroll
        for (int i = 0; i < 4; ++i) {
            float sv = 0.f;
#pragma unroll
            for (int nf = 0; nf < 4; ++nf)
                sv = fmaf(fast_tanh(acc[mf][nf][i] + ff[nf]), vv[nf], sv);
#pragma unroll
            for (int mm = 1; mm < 16; mm <<= 1) sv += __shfl_xor(sv, mm, 64);
            sums[i] = sv;
        }
        if (lr == 0)
#pragma unroll
            for (int i = 0; i < 4; ++i) ep[mf * 16 + g * 4 + i] = sums[i];
    }
}

__global__ __launch_bounds__(256) void k_softmax_fb(
        const float* __restrict__ e_part, float* __restrict__ a_out) {
    const int b = blockIdx.x, tid = threadIdx.x;
    const int lane = tid & 63, w = tid >> 6;
    __shared__ float red[4], red2[4];
    float ls[8]; float lmax = -1e30f;
#pragma unroll
    for (int i = 0; i < 8; ++i) {
        size_t mm = (size_t)b * T_ + i * 256 + tid;
        float sv = 0.f;
#pragma unroll
        for (int p = 0; p < 8; ++p) sv += e_part[(size_t)p * M_ + mm];
        ls[i] = sv; lmax = fmaxf(lmax, sv);
    }
#pragma unroll
    for (int mm = 1; mm < 64; mm <<= 1) lmax = fmaxf(lmax, __shfl_xor(lmax, mm, 64));
    if (lane == 0) red[w] = lmax;
    __syncthreads();
    float bmax = fmaxf(fmaxf(red[0], red[1]), fmaxf(red[2], red[3]));
    float lsum = 0.f;
#pragma unroll
    for (int i = 0; i < 8; ++i) { ls[i] = __expf(ls[i] - bmax); lsum += ls[i]; }
#pragma unroll
    for (int mm = 1; mm < 64; mm <<= 1) lsum += __shfl_xor(lsum, mm, 64);
    if (lane == 0) red2[w] = lsum;
    __syncthreads();
    float inv = 1.0f / (red2[0] + red2[1] + red2[2] + red2[3]);
#pragma unroll
    for (int i = 0; i < 8; ++i)
        a_out[(size_t)b * T_ + i * 256 + tid] = ls[i] * inv;
}

__global__ __launch_bounds__(256) void k_ctx_part_fb(
        const float* __restrict__ h, const float* __restrict__ a,
        float* __restrict__ c_part) {
    const int b = blockIdx.x, tc = blockIdx.y, tid = threadIdx.x;
    __shared__ float alds[128];
    if (tid < 128) alds[tid] = a[(size_t)b * T_ + tc * 128 + tid];
    __syncthreads();
    float4 acc = {0.f, 0.f, 0.f, 0.f};
    const float* hb = h + ((size_t)b * T_ + (size_t)tc * 128) * ENC_ + tid * 4;
    for (int t = 0; t < 128; ++t) {
        float av = alds[t];
        float4 hv = *(const float4*)(hb + (size_t)t * ENC_);
        acc.x = fmaf(av, hv.x, acc.x); acc.y = fmaf(av, hv.y, acc.y);
        acc.z = fmaf(av, hv.z, acc.z); acc.w = fmaf(av, hv.w, acc.w);
    }
    *(float4*)&c_part[((size_t)(tc * 64 + b)) * ENC_ + tid * 4] = acc;
}

__global__ __launch_bounds__(256) void k_ctx_final_fb(
        const float* __restrict__ c_part, float* __restrict__ c_out) {
    int idx = blockIdx.x * 256 + threadIdx.x;
    int off = idx * 4;
    float4 sv = {0.f, 0.f, 0.f, 0.f};
#pragma unroll
    for (int tc = 0; tc < 16; ++tc) {
        float4 v = *(const float4*)&c_part[(size_t)tc * 64 * 1024 + off];
        sv.x += v.x; sv.y += v.y; sv.z += v.z; sv.w += v.w;
    }
    *(float4*)&c_out[off] = sv;
}

extern "C" void kernel_launch(void* const* d_in, const int* in_sizes, int n_in,
                              void* d_out, int out_size, void* d_ws, size_t ws_size,
                              hipStream_t stream) {
    const float* h = (const float*)d_in[0];
    const float* s = (const float*)d_in[1];
    const float* U = (const float*)d_in[2];
    const float* W = (const float*)d_in[3];
    const float* V = (const float*)d_in[4];

    float* out   = (float*)d_out;
    float* c_out = out;                         // [64][1][1024]
    float* a_out = out + 64 * 1024;             // [64][2048][1]

    char* ws = (char*)d_ws;
    u16*   Ut = (u16*)ws;                                  // 1 MB
    float* f2 = (float*)(ws + (1 << 20));                  // 128 KB

    k_transpose_U<<<2048, 256, 0, stream>>>(U, Ut);
    k_f2<<<64, 256, 0, stream>>>(s, W, f2);

    const size_t NEED = (size_t)10 * 1024 * 1024 + (64 << 10);
    if (ws_size >= NEED) {
        float* e_full = (float*)(ws + 0x120000);           // 512 KB
        float* mpart  = (float*)(ws + 0x1A0000);           // 8 KB
        float* spart  = (float*)(ws + 0x1A2000);           // 8 KB
        float* mg_g   = (float*)(ws + 0x1A4000);           // 256 B
        float* sg_g   = (float*)(ws + 0x1A4100);           // 256 B
        float* opart  = (float*)(ws + 0x200000);           // 8 MB

        k_gemm_fused<<<NCH, 512, 0, stream>>>(h, Ut, f2, V,
                                              e_full, mpart, spart, opart);
        k_ctx_reduce<<<64, 256, 0, stream>>>(mpart, spart, opart,
                                             c_out, mg_g, sg_g);
        k_a_final<<<M_ / 256, 256, 0, stream>>>(e_full, mg_g, sg_g, a_out);
    } else {
        float* e_part = (float*)(ws + (1 << 20) + (128 << 10));  // 4 MB
        float* c_part = e_part;    // overlay after softmax
        k_gemm_e_fb<<<2048, 512, 0, stream>>>(h, Ut, f2, V, e_part);
        k_softmax_fb<<<64, 256, 0, stream>>>(e_part, a_out);
        dim3 gc(64, 16);
        k_ctx_part_fb<<<gc, 256, 0, stream>>>(h, a_out, c_part);
        k_ctx_final_fb<<<64, 256, 0, stream>>>(c_part, c_out);
    }
}